// Round 9
// baseline (659.526 us; speedup 1.0000x reference)
//
#include <hip/hip_runtime.h>
#include <math.h>

#define NN 100000
#define EE 1600000
#define KB 256          // buckets
#define RR 391          // ceil(NN / KB); srel < 391, dst < 2^17
#define CAP 8192        // per-bucket capacity (avg 6250, sigma ~76)
#define NPART 391       // part blocks (even blockIdx in D1), 4096 edges each

// ================= D0: P = W0 @ W1 @ [rowsum(w_rate0) | w_rate1 | w_alpha]; zero gcur + flags =================
// 1024 threads; 8 lanes per row (16 consecutive floats each) -> coalesced.

__global__ __launch_bounds__(1024) void k_pmat(const float* __restrict__ w_gcn0,
                                               const float* __restrict__ w_gcn1,
                                               const float* __restrict__ w_rate0,
                                               const float* __restrict__ w_rate1,
                                               const float* __restrict__ w_alpha,
                                               float* __restrict__ Pt0, float* __restrict__ Pt1,
                                               float* __restrict__ Pt2, int* __restrict__ gcur,
                                               int* __restrict__ flags) {
    __shared__ float V0[128], V1[128], V2[128];
    __shared__ float Q0[128], Q1[128], Q2[128];
    int t = threadIdx.x;
    if (t < KB) gcur[t] = 0;
    if (t == 1023) { flags[0] = 0; flags[1] = 0; }
    int r = t >> 3, seg = t & 7;
    {   // V0 = rowsum(w_rate0)
        const float* p = w_rate0 + r * 128 + seg * 16;
        float s = 0.f;
        #pragma unroll
        for (int k = 0; k < 16; ++k) s += p[k];
        s += __shfl_down(s, 4, 8); s += __shfl_down(s, 2, 8); s += __shfl_down(s, 1, 8);
        if (seg == 0) V0[r] = s;
    }
    if (t < 128) { V1[t] = w_rate1[t]; V2[t] = w_alpha[t]; }
    __syncthreads();
    {   // Q = w_gcn1 @ V
        const float* p = w_gcn1 + r * 128 + seg * 16;
        float q0 = 0.f, q1 = 0.f, q2 = 0.f;
        #pragma unroll
        for (int k = 0; k < 16; ++k) {
            float w = p[k]; int j = seg * 16 + k;
            q0 += w * V0[j]; q1 += w * V1[j]; q2 += w * V2[j];
        }
        q0 += __shfl_down(q0, 4, 8); q0 += __shfl_down(q0, 2, 8); q0 += __shfl_down(q0, 1, 8);
        q1 += __shfl_down(q1, 4, 8); q1 += __shfl_down(q1, 2, 8); q1 += __shfl_down(q1, 1, 8);
        q2 += __shfl_down(q2, 4, 8); q2 += __shfl_down(q2, 2, 8); q2 += __shfl_down(q2, 1, 8);
        if (seg == 0) { Q0[r] = q0; Q1[r] = q1; Q2[r] = q2; }
    }
    __syncthreads();
    {   // P = w_gcn0 @ Q
        const float* p = w_gcn0 + r * 128 + seg * 16;
        float q0 = 0.f, q1 = 0.f, q2 = 0.f;
        #pragma unroll
        for (int k = 0; k < 16; ++k) {
            float w = p[k]; int j = seg * 16 + k;
            q0 += w * Q0[j]; q1 += w * Q1[j]; q2 += w * Q2[j];
        }
        q0 += __shfl_down(q0, 4, 8); q0 += __shfl_down(q0, 2, 8); q0 += __shfl_down(q0, 1, 8);
        q1 += __shfl_down(q1, 4, 8); q1 += __shfl_down(q1, 2, 8); q1 += __shfl_down(q1, 1, 8);
        q2 += __shfl_down(q2, 4, 8); q2 += __shfl_down(q2, 2, 8); q2 += __shfl_down(q2, 1, 8);
        if (seg == 0) { Pt0[r] = q0; Pt1[r] = q1; Pt2[r] = q2; }
    }
}

// ================= D1: part (even blocks) ∥ proj (odd blocks) -> cnt tail (proj blocks id<256) =================
// 782 blocks x 512 thr. part: 4096 edges/block via int4. proj: 256 nodes/block, u4.xyz = h@P.
// cnt tail: spin on partdone==NPART (device-scope), then bucket degree count -> nrm[], u4.w.
// Spin safety: <=256 spinners, all waiting only on blocks of THIS dispatch; part blocks flow through
// remaining resident slots regardless of scheduling order.

__global__ __launch_bounds__(512) void k_d1(const int* __restrict__ src, const int* __restrict__ dst,
                                            int* __restrict__ gcur, unsigned int* __restrict__ pk,
                                            const float* __restrict__ h,
                                            const float* __restrict__ Pt0, const float* __restrict__ Pt1,
                                            const float* __restrict__ Pt2,
                                            float* __restrict__ nrm, float4* __restrict__ u4,
                                            int* __restrict__ partdone) {
    __shared__ int cnt[KB];
    __shared__ int base[KB];
    __shared__ float sP0[128], sP1[128], sP2[128];
    __shared__ int c[RR];
    int t = threadIdx.x;
    int role = blockIdx.x & 1;
    int id = blockIdx.x >> 1;

    if (role == 0) {
        // ---------------- partition: pk = dst | srel<<17 ----------------
        if (t < KB) cnt[t] = 0;
        __syncthreads();
        int e0 = id * 4096 + t * 8;
        unsigned int pkv[8];
        int bkt[8];
        if (e0 + 8 <= EE) {
            int4 sa = *(const int4*)(src + e0);
            int4 sb = *(const int4*)(src + e0 + 4);
            int4 da = *(const int4*)(dst + e0);
            int4 db = *(const int4*)(dst + e0 + 4);
            int ss[8] = { sa.x, sa.y, sa.z, sa.w, sb.x, sb.y, sb.z, sb.w };
            int dd[8] = { da.x, da.y, da.z, da.w, db.x, db.y, db.z, db.w };
            #pragma unroll
            for (int i = 0; i < 8; ++i) {
                int b = ss[i] / RR;
                bkt[i] = b;
                pkv[i] = (unsigned int)dd[i] | ((unsigned int)(ss[i] - b * RR) << 17);
                atomicAdd(&cnt[b], 1);
            }
        } else {
            #pragma unroll
            for (int i = 0; i < 8; ++i) {
                int e = e0 + i;
                if (e < EE) {
                    int s = src[e], d = dst[e];
                    int b = s / RR;
                    bkt[i] = b;
                    pkv[i] = (unsigned int)d | ((unsigned int)(s - b * RR) << 17);
                    atomicAdd(&cnt[b], 1);
                } else bkt[i] = -1;
            }
        }
        __syncthreads();
        if (t < KB) base[t] = cnt[t] ? atomicAdd(&gcur[t], cnt[t]) : 0;
        __syncthreads();
        if (t < KB) cnt[t] = 0;
        __syncthreads();
        #pragma unroll
        for (int i = 0; i < 8; ++i) {
            if (bkt[i] >= 0) {
                int rr = atomicAdd(&cnt[bkt[i]], 1);
                int rel = base[bkt[i]] + rr;
                if (rel < CAP) pk[bkt[i] * CAP + rel] = pkv[i];   // overflow guard (stat. impossible)
            }
        }
        __threadfence();                 // release: pk + gcur visible device-wide
        __syncthreads();
        if (t == 0) atomicAdd(partdone, 1);
    } else {
        // ---------------- raw projection u = h @ P ----------------
        if (t < 128) { sP0[t] = Pt0[t]; sP1[t] = Pt1[t]; sP2[t] = Pt2[t]; }
        __syncthreads();
        int hw = t >> 5;       // 0..15
        int l32 = t & 31;
        int c4 = l32 * 4;
        float4 c0 = *(const float4*)(sP0 + c4);
        float4 c1 = *(const float4*)(sP1 + c4);
        float4 c2 = *(const float4*)(sP2 + c4);
        int nlo = id * 256;
        for (int i0 = 0; i0 < 256; i0 += 16) {
            int node = nlo + i0 + hw;
            if (node < NN) {
                float4 hv = *(const float4*)(h + (size_t)node * 128 + c4);
                float p0v = hv.x * c0.x + hv.y * c0.y + hv.z * c0.z + hv.w * c0.w;
                float p1v = hv.x * c1.x + hv.y * c1.y + hv.z * c1.z + hv.w * c1.w;
                float p2v = hv.x * c2.x + hv.y * c2.y + hv.z * c2.z + hv.w * c2.w;
                #pragma unroll
                for (int off = 16; off > 0; off >>= 1) {
                    p0v += __shfl_down(p0v, off, 32);
                    p1v += __shfl_down(p1v, off, 32);
                    p2v += __shfl_down(p2v, off, 32);
                }
                if (l32 == 0) {
                    float* up = (float*)&u4[node];
                    *(float2*)up = make_float2(p0v, p1v);   // .xy
                    up[2] = p2v;                            // .z   (.w by cnt tail)
                }
            }
        }
        // ---------------- cnt tail (buckets 0..255) ----------------
        if (id < KB) {
            if (t < RR) c[t] = 0;
            if (t == 0) {
                while (atomicAdd(partdone, 0) < NPART) __builtin_amdgcn_s_sleep(2);
            }
            __syncthreads();
            __threadfence();             // acquire: see all part blocks' pk/gcur
            const unsigned int* P = pk + id * CAP;
            int m = gcur[id]; if (m > CAP) m = CAP;
            for (int i = t; i < m; i += 512) atomicAdd(&c[P[i] >> 17], 1);
            __syncthreads();
            int nlo2 = id * RR;
            int nn = NN - nlo2; if (nn > RR) nn = RR;
            if (t < nn) {
                float nv = rsqrtf((float)c[t]);
                nrm[nlo2 + t] = nv;
                ((float*)&u4[nlo2 + t])[3] = nv;   // .w only (disjoint from proj's .xyz)
            }
        }
    }
}

// ================= D2: agg1 -> flag barrier -> agg2 (one block per bucket, 1024 thr) =================
// agg1: acc += u[d].xyz * u[d].w;  z[s] = nrm[s]^2 * acc
// agg2: acc += z[d].xyz;           p[s] = nrm[s]   * acc
// All 256 blocks resident (1/CU) -> mid-kernel barrier safe.

__global__ __launch_bounds__(1024) void k_agg12(const unsigned int* __restrict__ pk,
                                                const int* __restrict__ gcur,
                                                const float4* __restrict__ u4, const float* __restrict__ nrm,
                                                float4* __restrict__ z4, float4* __restrict__ p4,
                                                int* __restrict__ aggdone) {
    __shared__ float s0[RR], s1[RR], s2[RR];
    int b = blockIdx.x;
    int t = threadIdx.x;
    int nlo = b * RR;
    int nn = NN - nlo; if (nn > RR) nn = RR;
    if (t < RR) { s0[t] = 0.f; s1[t] = 0.f; s2[t] = 0.f; }
    __syncthreads();
    const unsigned int* P = pk + b * CAP;
    int m = gcur[b]; if (m > CAP) m = CAP;
    // ---- phase 1 (2-deep pipelined) ----
    int i = t;
    for (; i + 1024 < m; i += 2048) {
        unsigned int wa = P[i];
        unsigned int wb = P[i + 1024];
        float4 va = u4[wa & 0x1FFFFu];
        float4 vb = u4[wb & 0x1FFFFu];
        int ra = (int)(wa >> 17), rb = (int)(wb >> 17);
        atomicAdd(&s0[ra], va.x * va.w); atomicAdd(&s1[ra], va.y * va.w); atomicAdd(&s2[ra], va.z * va.w);
        atomicAdd(&s0[rb], vb.x * vb.w); atomicAdd(&s1[rb], vb.y * vb.w); atomicAdd(&s2[rb], vb.z * vb.w);
    }
    if (i < m) {
        unsigned int wa = P[i];
        float4 va = u4[wa & 0x1FFFFu];
        int ra = (int)(wa >> 17);
        atomicAdd(&s0[ra], va.x * va.w); atomicAdd(&s1[ra], va.y * va.w); atomicAdd(&s2[ra], va.z * va.w);
    }
    __syncthreads();
    for (int j = t; j < nn; j += 1024) {
        float nv = nrm[nlo + j];
        float sc = nv * nv;
        z4[nlo + j] = make_float4(sc * s0[j], sc * s1[j], sc * s2[j], 0.f);
    }
    // ---- flag barrier across all 256 blocks ----
    __threadfence();
    __syncthreads();
    if (t == 0) {
        atomicAdd(aggdone, 1);
        while (atomicAdd(aggdone, 0) < KB) __builtin_amdgcn_s_sleep(2);
    }
    __syncthreads();
    __threadfence();
    if (t < RR) { s0[t] = 0.f; s1[t] = 0.f; s2[t] = 0.f; }
    __syncthreads();
    // ---- phase 2 (2-deep pipelined) ----
    i = t;
    for (; i + 1024 < m; i += 2048) {
        unsigned int wa = P[i];
        unsigned int wb = P[i + 1024];
        float4 va = z4[wa & 0x1FFFFu];
        float4 vb = z4[wb & 0x1FFFFu];
        int ra = (int)(wa >> 17), rb = (int)(wb >> 17);
        atomicAdd(&s0[ra], va.x); atomicAdd(&s1[ra], va.y); atomicAdd(&s2[ra], va.z);
        atomicAdd(&s0[rb], vb.x); atomicAdd(&s1[rb], vb.y); atomicAdd(&s2[rb], vb.z);
    }
    if (i < m) {
        unsigned int wa = P[i];
        float4 va = z4[wa & 0x1FFFFu];
        int ra = (int)(wa >> 17);
        atomicAdd(&s0[ra], va.x); atomicAdd(&s1[ra], va.y); atomicAdd(&s2[ra], va.z);
    }
    __syncthreads();
    for (int j = t; j < nn; j += 1024) {
        float nv = nrm[nlo + j];
        p4[nlo + j] = make_float4(nv * s0[j], nv * s1[j], nv * s2[j], 0.f);
    }
}

// ================= D3: edge outputs: 4 edges/thread, int4 index loads, float4 stores =================

__global__ __launch_bounds__(256) void k_edge(const int* __restrict__ esrc, const int* __restrict__ edst,
                                              const int* __restrict__ sfake, const int* __restrict__ dfake,
                                              const float4* __restrict__ p4, float* __restrict__ out) {
    int t = threadIdx.x;
    int e0 = blockIdx.x * 1024 + t * 4;
    if (e0 >= EE) return;
    int4 s4  = *(const int4*)(esrc + e0);
    int4 d4  = *(const int4*)(edst + e0);
    int4 sf4 = *(const int4*)(sfake + e0);
    int4 df4 = *(const int4*)(dfake + e0);
    int ss[4] = { s4.x, s4.y, s4.z, s4.w };
    int dd[4] = { d4.x, d4.y, d4.z, d4.w };
    int sf[4] = { sf4.x, sf4.y, sf4.z, sf4.w };
    int df[4] = { df4.x, df4.y, df4.z, df4.w };
    float o0[4], o1[4], o2[4], o3[4], o4[4], o5[4];
    #pragma unroll
    for (int j = 0; j < 4; ++j) {
        int sfj = sf[j]; sfj = sfj < 0 ? 0 : (sfj >= NN ? NN - 1 : sfj);
        int dfj = df[j]; dfj = dfj < 0 ? 0 : (dfj >= NN ? NN - 1 : dfj);
        float4 ps = p4[ss[j]], pd = p4[dd[j]], psf = p4[sfj], pdf = p4[dfj];
        o0[j] = expf(ps.x + pd.x);
        o1[j] = expf(ps.y + pd.y);
        o2[j] = 1.f / (1.f + expf(-(ps.z * pd.z)));
        o3[j] = expf(psf.x + 128.f * pdf.y);
        o4[j] = expf(psf.y + pdf.y);
        o5[j] = 1.f / (1.f + expf(-(ps.z * pdf.z)));
    }
    *(float4*)(out + e0)                  = make_float4(o0[0], o0[1], o0[2], o0[3]);
    *(float4*)(out + (size_t)EE + e0)     = make_float4(o1[0], o1[1], o1[2], o1[3]);
    *(float4*)(out + (size_t)2 * EE + e0) = make_float4(o2[0], o2[1], o2[2], o2[3]);
    *(float4*)(out + (size_t)3 * EE + e0) = make_float4(o3[0], o3[1], o3[2], o3[3]);
    *(float4*)(out + (size_t)4 * EE + e0) = make_float4(o4[0], o4[1], o4[2], o4[3]);
    *(float4*)(out + (size_t)5 * EE + e0) = make_float4(o5[0], o5[1], o5[2], o5[3]);
}

// ---------------- launch ----------------

extern "C" void kernel_launch(void* const* d_in, const int* in_sizes, int n_in,
                              void* d_out, int out_size, void* d_ws, size_t ws_size,
                              hipStream_t stream) {
    const float* h       = (const float*)d_in[0];
    const float* w_gcn0  = (const float*)d_in[1];
    const float* w_gcn1  = (const float*)d_in[2];
    const float* w_rate0 = (const float*)d_in[3];
    const float* w_rate1 = (const float*)d_in[4];
    const float* w_alpha = (const float*)d_in[5];
    const int* edge_src  = (const int*)d_in[6];
    const int* edge_dst  = (const int*)d_in[7];
    const int* src_fake  = (const int*)d_in[8];
    const int* dst_fake  = (const int*)d_in[9];
    float* out = (float*)d_out;

    char* p = (char*)d_ws;
    auto alloc = [&](size_t bytes) {
        char* r = p;
        p += (bytes + 255) & ~(size_t)255;
        return r;
    };
    unsigned int* pk = (unsigned int*)alloc((size_t)KB * CAP * 4);   // 8.4 MB
    int* gcur   = (int*)alloc(KB * 4);
    int* flags  = (int*)alloc(256);                                  // [0]=partdone, [1]=aggdone
    float* nrm  = (float*)alloc((size_t)NN * 4);
    float4* u4  = (float4*)alloc((size_t)NN * 16);
    float4* z4  = (float4*)alloc((size_t)NN * 16);
    float4* p4  = (float4*)alloc((size_t)NN * 16);
    float* Pt0  = (float*)alloc(512);
    float* Pt1  = (float*)alloc(512);
    float* Pt2  = (float*)alloc(512);

    k_pmat<<<1, 1024, 0, stream>>>(w_gcn0, w_gcn1, w_rate0, w_rate1, w_alpha,
                                   Pt0, Pt1, Pt2, gcur, flags);
    k_d1<<<782, 512, 0, stream>>>(edge_src, edge_dst, gcur, pk, h, Pt0, Pt1, Pt2,
                                  nrm, u4, &flags[0]);
    k_agg12<<<KB, 1024, 0, stream>>>(pk, gcur, u4, nrm, z4, p4, &flags[1]);
    k_edge<<<(EE + 1023) / 1024, 256, 0, stream>>>(edge_src, edge_dst, src_fake, dst_fake, p4, out);
}

// Round 10
// 385.496 us; speedup vs baseline: 1.7109x; 1.7109x over previous
//
#include <hip/hip_runtime.h>
#include <hip/hip_cooperative_groups.h>
#include <math.h>

namespace cg = cooperative_groups;

#define NN 100000
#define EE 1600000
#define KB 256          // buckets == blocks == CUs
#define RR 391          // ceil(NN / KB); srel < 391, dst < 2^17
#define CAP 8192        // fixed per-bucket capacity (avg 6250, sigma ~76)
#define EPB 6250        // EE / KB exactly
#define EITER 7         // ceil(EPB / 1024)

// ---------------- init per-bucket append cursors ----------------

__global__ __launch_bounds__(256) void k_init(int* __restrict__ gcur) {
    gcur[threadIdx.x] = 0;
}

// Single cooperative kernel: [part(all) ∥ pmat(block0)] -> (cnt+nrm+proj) -> agg1 -> agg2 -> edge_out
// Block b owns bucket b (nodes [b*RR, ...)) AND edge chunk [b*EPB, (b+1)*EPB).
// Bucket pk, nrm, and the chunk's (s,d) live in LDS across grid.sync()s.  (Structure verified in R2.)

__global__ __launch_bounds__(1024) void k_fused(
    const float* __restrict__ h,
    const float* __restrict__ w_gcn0,
    const float* __restrict__ w_gcn1,
    const float* __restrict__ w_rate0,
    const float* __restrict__ w_rate1,
    const float* __restrict__ w_alpha,
    const int* __restrict__ esrc,
    const int* __restrict__ edst,
    const int* __restrict__ sfake,
    const int* __restrict__ dfake,
    unsigned int* __restrict__ pk,
    int* __restrict__ gcur,
    float4* __restrict__ w4,
    float4* __restrict__ z4,
    float4* __restrict__ p4,
    float* __restrict__ Pt0, float* __restrict__ Pt1, float* __restrict__ Pt2,
    float* __restrict__ out)
{
    __shared__ unsigned int s_pk[CAP];          // 32 KB  bucket edges (phases 1-3)
    __shared__ int   s_s[EPB];                  // 25 KB  chunk src (phase 0 -> 4)
    __shared__ int   s_d[EPB];                  // 25 KB  chunk dst (phase 0 -> 4)
    __shared__ alignas(16) float sP0[128];      // P columns (phase 1)
    __shared__ alignas(16) float sP1[128];
    __shared__ alignas(16) float sP2[128];
    __shared__ int   c[RR];                     // degree counts
    __shared__ float s_nrm[RR];                 // deg^-0.5 (phase 1 -> 2,3)
    __shared__ float s0[RR], s1[RR], s2[RR];    // accumulators (also pmat temps, block 0, phase 0)
    __shared__ int   cnt[KB], base[KB];         // partition histogram

    cg::grid_group grid = cg::this_grid();
    const int b = blockIdx.x;
    const int t = threadIdx.x;

    // ---------- phase 0: partition my chunk (all blocks); block 0 additionally computes P ----------
    if (t < KB) cnt[t] = 0;
    __syncthreads();
    const int e0 = b * EPB;
    unsigned int pkv[EITER];
    int bkt[EITER];
    #pragma unroll
    for (int r = 0; r < EITER; ++r) {
        int i = r * 1024 + t;
        if (i < EPB) {
            int s = esrc[e0 + i];
            int d = edst[e0 + i];
            s_s[i] = s; s_d[i] = d;
            int bb = s / RR;
            bkt[r] = bb;
            pkv[r] = (unsigned int)d | ((unsigned int)(s - bb * RR) << 17);
            atomicAdd(&cnt[bb], 1);
        } else bkt[r] = -1;
    }
    __syncthreads();
    if (t < KB) base[t] = cnt[t] ? atomicAdd(&gcur[t], cnt[t]) : 0;   // RELATIVE cursor (gcur zeroed by k_init)
    __syncthreads();
    if (t < KB) cnt[t] = 0;
    __syncthreads();
    #pragma unroll
    for (int r = 0; r < EITER; ++r) {
        if (bkt[r] >= 0) {
            int rr = atomicAdd(&cnt[bkt[r]], 1);
            int rel = base[bkt[r]] + rr;
            if (rel < CAP) pk[bkt[r] * CAP + rel] = pkv[r];   // overflow guard (stat. impossible)
        }
    }

    if (b == 0) {
        // ---- coalesced pmat (R5-verified body): P = W0 @ W1 @ [rowsum(w_rate0) | w_rate1 | w_alpha] ----
        __syncthreads();
        int r = t >> 3, seg = t & 7;           // 8 lanes/row, 16 consecutive floats each
        {   // V0 = rowsum(w_rate0)  -> s0[0..127]
            const float* p = w_rate0 + r * 128 + seg * 16;
            float s = 0.f;
            #pragma unroll
            for (int k = 0; k < 16; ++k) s += p[k];
            s += __shfl_down(s, 4, 8); s += __shfl_down(s, 2, 8); s += __shfl_down(s, 1, 8);
            if (seg == 0) s0[r] = s;
        }
        if (t < 128) { s1[t] = w_rate1[t]; s2[t] = w_alpha[t]; }
        __syncthreads();
        {   // Q = w_gcn1 @ V  -> s0/s1/s2[128..255]
            const float* p = w_gcn1 + r * 128 + seg * 16;
            float q0 = 0.f, q1 = 0.f, q2 = 0.f;
            #pragma unroll
            for (int k = 0; k < 16; ++k) {
                float w = p[k]; int j = seg * 16 + k;
                q0 += w * s0[j]; q1 += w * s1[j]; q2 += w * s2[j];
            }
            q0 += __shfl_down(q0, 4, 8); q0 += __shfl_down(q0, 2, 8); q0 += __shfl_down(q0, 1, 8);
            q1 += __shfl_down(q1, 4, 8); q1 += __shfl_down(q1, 2, 8); q1 += __shfl_down(q1, 1, 8);
            q2 += __shfl_down(q2, 4, 8); q2 += __shfl_down(q2, 2, 8); q2 += __shfl_down(q2, 1, 8);
            if (seg == 0) { s0[128 + r] = q0; s1[128 + r] = q1; s2[128 + r] = q2; }
        }
        __syncthreads();
        {   // P = w_gcn0 @ Q  -> global Pt
            const float* p = w_gcn0 + r * 128 + seg * 16;
            float q0 = 0.f, q1 = 0.f, q2 = 0.f;
            #pragma unroll
            for (int k = 0; k < 16; ++k) {
                float w = p[k]; int j = seg * 16 + k;
                q0 += w * s0[128 + j]; q1 += w * s1[128 + j]; q2 += w * s2[128 + j];
            }
            q0 += __shfl_down(q0, 4, 8); q0 += __shfl_down(q0, 2, 8); q0 += __shfl_down(q0, 1, 8);
            q1 += __shfl_down(q1, 4, 8); q1 += __shfl_down(q1, 2, 8); q1 += __shfl_down(q1, 1, 8);
            q2 += __shfl_down(q2, 4, 8); q2 += __shfl_down(q2, 2, 8); q2 += __shfl_down(q2, 1, 8);
            if (seg == 0) { Pt0[r] = q0; Pt1[r] = q1; Pt2[r] = q2; }
        }
    }
    grid.sync();

    // ---------- phase 1: bucket b: load pk -> LDS, degrees, nrm, w = nrm*(h@P) ----------
    const int P0 = b * CAP;
    int m = gcur[b]; if (m > CAP) m = CAP;
    const int nlo = b * RR;
    const int nn  = (NN - nlo) < RR ? (NN - nlo) : RR;
    if (t < 128) { sP0[t] = Pt0[t]; sP1[t] = Pt1[t]; sP2[t] = Pt2[t]; }
    if (t < RR) c[t] = 0;
    __syncthreads();
    for (int i = t; i < m; i += 1024) {
        unsigned int w = pk[P0 + i];
        s_pk[i] = w;
        atomicAdd(&c[w >> 17], 1);
    }
    __syncthreads();
    if (t < nn) s_nrm[t] = rsqrtf((float)c[t]);
    __syncthreads();
    {
        const int hw  = t >> 5;        // half-wave 0..31
        const int l32 = t & 31;
        const int c4  = l32 * 4;
        float4 c0 = *(const float4*)(sP0 + c4);
        float4 c1 = *(const float4*)(sP1 + c4);
        float4 c2 = *(const float4*)(sP2 + c4);
        for (int i0 = 0; i0 < nn; i0 += 32) {
            int i = i0 + hw;
            if (i >= nn) break;
            int node = nlo + i;
            float4 hv = *(const float4*)(h + (size_t)node * 128 + c4);
            float p0v = hv.x * c0.x + hv.y * c0.y + hv.z * c0.z + hv.w * c0.w;
            float p1v = hv.x * c1.x + hv.y * c1.y + hv.z * c1.z + hv.w * c1.w;
            float p2v = hv.x * c2.x + hv.y * c2.y + hv.z * c2.z + hv.w * c2.w;
            #pragma unroll
            for (int off = 16; off > 0; off >>= 1) {
                p0v += __shfl_down(p0v, off, 32);
                p1v += __shfl_down(p1v, off, 32);
                p2v += __shfl_down(p2v, off, 32);
            }
            if (l32 == 0) {
                float nv = s_nrm[i];
                w4[node] = make_float4(nv * p0v, nv * p1v, nv * p2v, 0.f);
            }
        }
    }
    grid.sync();

    // ---------- phase 2: z = nrm^2 * (A w)   (pk from LDS) ----------
    if (t < RR) { s0[t] = 0.f; s1[t] = 0.f; s2[t] = 0.f; }
    __syncthreads();
    for (int i = t; i < m; i += 1024) {
        unsigned int w = s_pk[i];
        float4 v = w4[w & 0x1FFFFu];
        int srel = (int)(w >> 17);
        atomicAdd(&s0[srel], v.x);
        atomicAdd(&s1[srel], v.y);
        atomicAdd(&s2[srel], v.z);
    }
    __syncthreads();
    if (t < nn) {
        float nv = s_nrm[t], sc = nv * nv;
        z4[nlo + t] = make_float4(sc * s0[t], sc * s1[t], sc * s2[t], 0.f);
    }
    grid.sync();

    // ---------- phase 3: p = nrm * (A z) ----------
    if (t < RR) { s0[t] = 0.f; s1[t] = 0.f; s2[t] = 0.f; }
    __syncthreads();
    for (int i = t; i < m; i += 1024) {
        unsigned int w = s_pk[i];
        float4 v = z4[w & 0x1FFFFu];
        int srel = (int)(w >> 17);
        atomicAdd(&s0[srel], v.x);
        atomicAdd(&s1[srel], v.y);
        atomicAdd(&s2[srel], v.z);
    }
    __syncthreads();
    if (t < nn) {
        float nv = s_nrm[t];
        p4[nlo + t] = make_float4(nv * s0[t], nv * s1[t], nv * s2[t], 0.f);
    }
    grid.sync();

    // ---------- phase 4: edge outputs for my chunk ((s,d) from LDS) ----------
    #pragma unroll
    for (int r = 0; r < EITER; ++r) {
        int i = r * 1024 + t;
        if (i < EPB) {
            int e = e0 + i;
            int s = s_s[i], d = s_d[i];
            int sf = sfake[e]; sf = sf < 0 ? 0 : (sf >= NN ? NN - 1 : sf);
            int df = dfake[e]; df = df < 0 ? 0 : (df >= NN ? NN - 1 : df);
            float4 ps = p4[s], pd = p4[d], psf = p4[sf], pdf = p4[df];
            out[e]                  = expf(ps.x + pd.x);
            out[(size_t)EE + e]     = expf(ps.y + pd.y);
            out[(size_t)2 * EE + e] = 1.f / (1.f + expf(-(ps.z * pd.z)));
            out[(size_t)3 * EE + e] = expf(psf.x + 128.f * pdf.y);
            out[(size_t)4 * EE + e] = expf(psf.y + pdf.y);
            out[(size_t)5 * EE + e] = 1.f / (1.f + expf(-(ps.z * pdf.z)));
        }
    }
}

// ---------------- launch ----------------

extern "C" void kernel_launch(void* const* d_in, const int* in_sizes, int n_in,
                              void* d_out, int out_size, void* d_ws, size_t ws_size,
                              hipStream_t stream) {
    const float* h       = (const float*)d_in[0];
    const float* w_gcn0  = (const float*)d_in[1];
    const float* w_gcn1  = (const float*)d_in[2];
    const float* w_rate0 = (const float*)d_in[3];
    const float* w_rate1 = (const float*)d_in[4];
    const float* w_alpha = (const float*)d_in[5];
    const int* edge_src  = (const int*)d_in[6];
    const int* edge_dst  = (const int*)d_in[7];
    const int* src_fake  = (const int*)d_in[8];
    const int* dst_fake  = (const int*)d_in[9];
    float* out = (float*)d_out;

    char* p = (char*)d_ws;
    auto alloc = [&](size_t bytes) {
        char* r = p;
        p += (bytes + 255) & ~(size_t)255;
        return r;
    };
    unsigned int* pk = (unsigned int*)alloc((size_t)KB * CAP * 4);   // 8.4 MB
    int* gcur   = (int*)alloc(KB * 4);
    float4* w4  = (float4*)alloc((size_t)NN * 16);
    float4* z4  = (float4*)alloc((size_t)NN * 16);
    float4* p4  = (float4*)alloc((size_t)NN * 16);
    float* Pt0  = (float*)alloc(512);
    float* Pt1  = (float*)alloc(512);
    float* Pt2  = (float*)alloc(512);

    k_init<<<1, KB, 0, stream>>>(gcur);

    void* args[] = { &h, &w_gcn0, &w_gcn1, &w_rate0, &w_rate1, &w_alpha,
                     &edge_src, &edge_dst, &src_fake, &dst_fake,
                     &pk, &gcur, &w4, &z4, &p4, &Pt0, &Pt1, &Pt2, &out };
    hipLaunchCooperativeKernel((void*)k_fused, dim3(KB), dim3(1024), args, 0, stream);
}

// Round 11
// 246.998 us; speedup vs baseline: 2.6702x; 1.5607x over previous
//
#include <hip/hip_runtime.h>
#include <math.h>

#define NN 100000
#define EE 1600000
#define KB 256          // buckets
#define RR 391          // ceil(NN / KB); srel < 391, dst < 2^17
#define CAP 8192        // per-bucket capacity (avg 6250, sigma ~76)
#define NPART 391       // part blocks: 4096 edges each

// ---------------- D0: zero per-bucket append cursors ----------------

__global__ __launch_bounds__(256) void k_init(int* __restrict__ gcur) {
    gcur[threadIdx.x] = 0;
}

// ================= D1: part (even blocks) ∥ [pmat + proj] (odd blocks) =================
// 782 blocks x 512 thr. part: 4096 edges/block via int4, pk = dst | srel<<17.
// proj: per-block COALESCED pmat (weights L2-hot) -> u4.xyz = h @ P (raw; .w filled by cnt).

__global__ __launch_bounds__(512) void k_part_proj(const int* __restrict__ src, const int* __restrict__ dst,
                                                   int* __restrict__ gcur, unsigned int* __restrict__ pk,
                                                   const float* __restrict__ h,
                                                   const float* __restrict__ w_gcn0,
                                                   const float* __restrict__ w_gcn1,
                                                   const float* __restrict__ w_rate0,
                                                   const float* __restrict__ w_rate1,
                                                   const float* __restrict__ w_alpha,
                                                   float4* __restrict__ u4) {
    __shared__ int cnt[KB];
    __shared__ int base[KB];
    __shared__ float V0[128], V1[128], V2[128];
    __shared__ float Q0[128], Q1[128], Q2[128];
    __shared__ alignas(16) float sP0[128], sP1[128], sP2[128];
    int t = threadIdx.x;
    int role = blockIdx.x & 1;
    int id = blockIdx.x >> 1;

    if (role == 0) {
        // ---------------- partition ----------------
        if (t < KB) cnt[t] = 0;
        __syncthreads();
        int e0 = id * 4096 + t * 8;
        unsigned int pkv[8];
        int bkt[8];
        if (e0 + 8 <= EE) {
            int4 sa = *(const int4*)(src + e0);
            int4 sb = *(const int4*)(src + e0 + 4);
            int4 da = *(const int4*)(dst + e0);
            int4 db = *(const int4*)(dst + e0 + 4);
            int ss[8] = { sa.x, sa.y, sa.z, sa.w, sb.x, sb.y, sb.z, sb.w };
            int dd[8] = { da.x, da.y, da.z, da.w, db.x, db.y, db.z, db.w };
            #pragma unroll
            for (int i = 0; i < 8; ++i) {
                int b = ss[i] / RR;
                bkt[i] = b;
                pkv[i] = (unsigned int)dd[i] | ((unsigned int)(ss[i] - b * RR) << 17);
                atomicAdd(&cnt[b], 1);
            }
        } else {
            #pragma unroll
            for (int i = 0; i < 8; ++i) {
                int e = e0 + i;
                if (e < EE) {
                    int s = src[e], d = dst[e];
                    int b = s / RR;
                    bkt[i] = b;
                    pkv[i] = (unsigned int)d | ((unsigned int)(s - b * RR) << 17);
                    atomicAdd(&cnt[b], 1);
                } else bkt[i] = -1;
            }
        }
        __syncthreads();
        if (t < KB) base[t] = cnt[t] ? atomicAdd(&gcur[t], cnt[t]) : 0;   // gcur zeroed by k_init
        __syncthreads();
        if (t < KB) cnt[t] = 0;
        __syncthreads();
        #pragma unroll
        for (int i = 0; i < 8; ++i) {
            if (bkt[i] >= 0) {
                int rr = atomicAdd(&cnt[bkt[i]], 1);
                int rel = base[bkt[i]] + rr;
                if (rel < CAP) pk[bkt[i] * CAP + rel] = pkv[i];   // overflow guard (stat. impossible)
            }
        }
    } else {
        // ---------------- per-block coalesced pmat: P = W0 @ W1 @ [rowsum(w_rate0)|w_rate1|w_alpha] ----------------
        int r = t >> 2, seg = t & 3;       // 4 lanes/row, 32 consecutive floats (8 float4) each
        {   // V0 = rowsum(w_rate0)
            const float4* pp = (const float4*)(w_rate0 + r * 128 + seg * 32);
            float s = 0.f;
            #pragma unroll
            for (int k = 0; k < 8; ++k) { float4 v = pp[k]; s += v.x + v.y + v.z + v.w; }
            s += __shfl_down(s, 2, 4); s += __shfl_down(s, 1, 4);
            if (seg == 0) V0[r] = s;
        }
        if (t < 128) { V1[t] = w_rate1[t]; V2[t] = w_alpha[t]; }
        __syncthreads();
        {   // Q = w_gcn1 @ V
            const float4* pp = (const float4*)(w_gcn1 + r * 128 + seg * 32);
            float q0 = 0.f, q1 = 0.f, q2 = 0.f;
            #pragma unroll
            for (int k = 0; k < 8; ++k) {
                float4 w = pp[k];
                int j = seg * 32 + k * 4;
                q0 += w.x * V0[j] + w.y * V0[j+1] + w.z * V0[j+2] + w.w * V0[j+3];
                q1 += w.x * V1[j] + w.y * V1[j+1] + w.z * V1[j+2] + w.w * V1[j+3];
                q2 += w.x * V2[j] + w.y * V2[j+1] + w.z * V2[j+2] + w.w * V2[j+3];
            }
            q0 += __shfl_down(q0, 2, 4); q0 += __shfl_down(q0, 1, 4);
            q1 += __shfl_down(q1, 2, 4); q1 += __shfl_down(q1, 1, 4);
            q2 += __shfl_down(q2, 2, 4); q2 += __shfl_down(q2, 1, 4);
            if (seg == 0) { Q0[r] = q0; Q1[r] = q1; Q2[r] = q2; }
        }
        __syncthreads();
        {   // P = w_gcn0 @ Q -> sP (LDS only; no global round-trip)
            const float4* pp = (const float4*)(w_gcn0 + r * 128 + seg * 32);
            float q0 = 0.f, q1 = 0.f, q2 = 0.f;
            #pragma unroll
            for (int k = 0; k < 8; ++k) {
                float4 w = pp[k];
                int j = seg * 32 + k * 4;
                q0 += w.x * Q0[j] + w.y * Q0[j+1] + w.z * Q0[j+2] + w.w * Q0[j+3];
                q1 += w.x * Q1[j] + w.y * Q1[j+1] + w.z * Q1[j+2] + w.w * Q1[j+3];
                q2 += w.x * Q2[j] + w.y * Q2[j+1] + w.z * Q2[j+2] + w.w * Q2[j+3];
            }
            q0 += __shfl_down(q0, 2, 4); q0 += __shfl_down(q0, 1, 4);
            q1 += __shfl_down(q1, 2, 4); q1 += __shfl_down(q1, 1, 4);
            q2 += __shfl_down(q2, 2, 4); q2 += __shfl_down(q2, 1, 4);
            if (seg == 0) { sP0[r] = q0; sP1[r] = q1; sP2[r] = q2; }
        }
        __syncthreads();
        // ---------------- raw projection u = h @ P ----------------
        int hw = t >> 5;       // 0..15
        int l32 = t & 31;
        int c4 = l32 * 4;
        float4 c0 = *(const float4*)(sP0 + c4);
        float4 c1 = *(const float4*)(sP1 + c4);
        float4 c2 = *(const float4*)(sP2 + c4);
        int nlo = id * 256;
        for (int i0 = 0; i0 < 256; i0 += 16) {
            int node = nlo + i0 + hw;
            if (node < NN) {
                float4 hv = *(const float4*)(h + (size_t)node * 128 + c4);
                float p0v = hv.x * c0.x + hv.y * c0.y + hv.z * c0.z + hv.w * c0.w;
                float p1v = hv.x * c1.x + hv.y * c1.y + hv.z * c1.z + hv.w * c1.w;
                float p2v = hv.x * c2.x + hv.y * c2.y + hv.z * c2.z + hv.w * c2.w;
                #pragma unroll
                for (int off = 16; off > 0; off >>= 1) {
                    p0v += __shfl_down(p0v, off, 32);
                    p1v += __shfl_down(p1v, off, 32);
                    p2v += __shfl_down(p2v, off, 32);
                }
                if (l32 == 0) {
                    float* up = (float*)&u4[node];
                    *(float2*)up = make_float2(p0v, p1v);   // .xy
                    up[2] = p2v;                            // .z   (.w written by k_cnt)
                }
            }
        }
    }
}

// ================= D2: cnt: degrees from pk -> nrm[]; stow nrm into u4.w =================

__global__ __launch_bounds__(1024) void k_cnt(const unsigned int* __restrict__ pk,
                                              const int* __restrict__ gcur,
                                              float* __restrict__ nrm, float4* __restrict__ u4) {
    __shared__ int c[RR];
    int b = blockIdx.x;
    int t = threadIdx.x;
    int nlo = b * RR;
    int nn = NN - nlo; if (nn > RR) nn = RR;
    if (nn <= 0) return;
    if (t < RR) c[t] = 0;
    __syncthreads();
    const unsigned int* P = pk + b * CAP;
    int m = gcur[b]; if (m > CAP) m = CAP;
    for (int i = t; i < m; i += 1024) atomicAdd(&c[P[i] >> 17], 1);
    __syncthreads();
    if (t < nn) {
        float nv = rsqrtf((float)c[t]);
        nrm[nlo + t] = nv;
        ((float*)&u4[nlo + t])[3] = nv;    // .w only
    }
}

// ================= D3/D4: bucketed aggregation; 4-deep pipelined gathers =================
// MODE 1: value = T[d].xyz * T[d].w (u4, .w = nrm[d]); store z = nrm^2 * acc
// MODE 2: value = T[d].xyz (z4 pre-scaled);            store p = nrm * acc

template<int MODE>
__global__ __launch_bounds__(1024) void k_agg(const unsigned int* __restrict__ pk,
                                              const int* __restrict__ gcur,
                                              const float4* __restrict__ T, const float* __restrict__ nrm,
                                              float4* __restrict__ outv) {
    __shared__ float s0[RR], s1[RR], s2[RR];
    int b = blockIdx.x;
    int t = threadIdx.x;
    int nlo = b * RR;
    int nn = NN - nlo; if (nn > RR) nn = RR;
    if (nn <= 0) return;
    if (t < RR) { s0[t] = 0.f; s1[t] = 0.f; s2[t] = 0.f; }
    __syncthreads();
    const unsigned int* P = pk + b * CAP;
    int m = gcur[b]; if (m > CAP) m = CAP;
    int i = t;
    for (; i + 3072 < m; i += 4096) {
        unsigned int w0 = P[i];
        unsigned int w1 = P[i + 1024];
        unsigned int w2 = P[i + 2048];
        unsigned int w3 = P[i + 3072];
        float4 v0 = T[w0 & 0x1FFFFu];
        float4 v1 = T[w1 & 0x1FFFFu];
        float4 v2 = T[w2 & 0x1FFFFu];
        float4 v3 = T[w3 & 0x1FFFFu];
        if (MODE == 1) {
            v0.x *= v0.w; v0.y *= v0.w; v0.z *= v0.w;
            v1.x *= v1.w; v1.y *= v1.w; v1.z *= v1.w;
            v2.x *= v2.w; v2.y *= v2.w; v2.z *= v2.w;
            v3.x *= v3.w; v3.y *= v3.w; v3.z *= v3.w;
        }
        int r0 = (int)(w0 >> 17), r1 = (int)(w1 >> 17), r2 = (int)(w2 >> 17), r3 = (int)(w3 >> 17);
        atomicAdd(&s0[r0], v0.x); atomicAdd(&s1[r0], v0.y); atomicAdd(&s2[r0], v0.z);
        atomicAdd(&s0[r1], v1.x); atomicAdd(&s1[r1], v1.y); atomicAdd(&s2[r1], v1.z);
        atomicAdd(&s0[r2], v2.x); atomicAdd(&s1[r2], v2.y); atomicAdd(&s2[r2], v2.z);
        atomicAdd(&s0[r3], v3.x); atomicAdd(&s1[r3], v3.y); atomicAdd(&s2[r3], v3.z);
    }
    for (; i < m; i += 1024) {
        unsigned int wa = P[i];
        float4 va = T[wa & 0x1FFFFu];
        float ax = va.x, ay = va.y, az = va.z;
        if (MODE == 1) { ax *= va.w; ay *= va.w; az *= va.w; }
        int ra = (int)(wa >> 17);
        atomicAdd(&s0[ra], ax); atomicAdd(&s1[ra], ay); atomicAdd(&s2[ra], az);
    }
    __syncthreads();
    for (int j = t; j < nn; j += 1024) {
        float nv = nrm[nlo + j];
        float sc = (MODE == 1) ? nv * nv : nv;
        outv[nlo + j] = make_float4(sc * s0[j], sc * s1[j], sc * s2[j], 0.f);
    }
}

// ================= D5: edge outputs: 4 edges/thread, int4 index loads, float4 stores =================

__global__ __launch_bounds__(256) void k_edge(const int* __restrict__ esrc, const int* __restrict__ edst,
                                              const int* __restrict__ sfake, const int* __restrict__ dfake,
                                              const float4* __restrict__ p4, float* __restrict__ out) {
    int t = threadIdx.x;
    int e0 = blockIdx.x * 1024 + t * 4;
    if (e0 >= EE) return;
    int4 s4  = *(const int4*)(esrc + e0);
    int4 d4  = *(const int4*)(edst + e0);
    int4 sf4 = *(const int4*)(sfake + e0);
    int4 df4 = *(const int4*)(dfake + e0);
    int ss[4] = { s4.x, s4.y, s4.z, s4.w };
    int dd[4] = { d4.x, d4.y, d4.z, d4.w };
    int sf[4] = { sf4.x, sf4.y, sf4.z, sf4.w };
    int df[4] = { df4.x, df4.y, df4.z, df4.w };
    float o0[4], o1[4], o2[4], o3[4], o4[4], o5[4];
    #pragma unroll
    for (int j = 0; j < 4; ++j) {
        int sfj = sf[j]; sfj = sfj < 0 ? 0 : (sfj >= NN ? NN - 1 : sfj);
        int dfj = df[j]; dfj = dfj < 0 ? 0 : (dfj >= NN ? NN - 1 : dfj);
        float4 ps = p4[ss[j]], pd = p4[dd[j]], psf = p4[sfj], pdf = p4[dfj];
        o0[j] = expf(ps.x + pd.x);
        o1[j] = expf(ps.y + pd.y);
        o2[j] = 1.f / (1.f + expf(-(ps.z * pd.z)));
        o3[j] = expf(psf.x + 128.f * pdf.y);
        o4[j] = expf(psf.y + pdf.y);
        o5[j] = 1.f / (1.f + expf(-(ps.z * pdf.z)));
    }
    *(float4*)(out + e0)                  = make_float4(o0[0], o0[1], o0[2], o0[3]);
    *(float4*)(out + (size_t)EE + e0)     = make_float4(o1[0], o1[1], o1[2], o1[3]);
    *(float4*)(out + (size_t)2 * EE + e0) = make_float4(o2[0], o2[1], o2[2], o2[3]);
    *(float4*)(out + (size_t)3 * EE + e0) = make_float4(o3[0], o3[1], o3[2], o3[3]);
    *(float4*)(out + (size_t)4 * EE + e0) = make_float4(o4[0], o4[1], o4[2], o4[3]);
    *(float4*)(out + (size_t)5 * EE + e0) = make_float4(o5[0], o5[1], o5[2], o5[3]);
}

// ---------------- launch ----------------

extern "C" void kernel_launch(void* const* d_in, const int* in_sizes, int n_in,
                              void* d_out, int out_size, void* d_ws, size_t ws_size,
                              hipStream_t stream) {
    const float* h       = (const float*)d_in[0];
    const float* w_gcn0  = (const float*)d_in[1];
    const float* w_gcn1  = (const float*)d_in[2];
    const float* w_rate0 = (const float*)d_in[3];
    const float* w_rate1 = (const float*)d_in[4];
    const float* w_alpha = (const float*)d_in[5];
    const int* edge_src  = (const int*)d_in[6];
    const int* edge_dst  = (const int*)d_in[7];
    const int* src_fake  = (const int*)d_in[8];
    const int* dst_fake  = (const int*)d_in[9];
    float* out = (float*)d_out;

    char* p = (char*)d_ws;
    auto alloc = [&](size_t bytes) {
        char* r = p;
        p += (bytes + 255) & ~(size_t)255;
        return r;
    };
    unsigned int* pk = (unsigned int*)alloc((size_t)KB * CAP * 4);   // 8.4 MB
    int* gcur   = (int*)alloc(KB * 4);
    float* nrm  = (float*)alloc((size_t)NN * 4);
    float4* u4  = (float4*)alloc((size_t)NN * 16);
    float4* z4  = (float4*)alloc((size_t)NN * 16);
    float4* p4  = (float4*)alloc((size_t)NN * 16);

    k_init<<<1, KB, 0, stream>>>(gcur);
    k_part_proj<<<2 * NPART, 512, 0, stream>>>(edge_src, edge_dst, gcur, pk, h,
                                               w_gcn0, w_gcn1, w_rate0, w_rate1, w_alpha, u4);
    k_cnt<<<KB, 1024, 0, stream>>>(pk, gcur, nrm, u4);
    k_agg<1><<<KB, 1024, 0, stream>>>(pk, gcur, u4, nrm, z4);
    k_agg<2><<<KB, 1024, 0, stream>>>(pk, gcur, z4, nrm, p4);
    k_edge<<<(EE + 1023) / 1024, 256, 0, stream>>>(edge_src, edge_dst, src_fake, dst_fake, p4, out);
}

// Round 12
// 225.669 us; speedup vs baseline: 2.9225x; 1.0945x over previous
//
#include <hip/hip_runtime.h>
#include <math.h>

#define NN 100000
#define EE 1600000
#define KB 256          // buckets
#define RR 391          // ceil(NN / KB); srel < 391, dst < 2^17
#define CAP 8192        // per-bucket capacity (avg 6250, sigma ~76)
#define NPART 391       // part blocks: 4096 edges each

// ================= D0: P = W0 @ W1 @ [rowsum(w_rate0) | w_rate1 | w_alpha]; also zero gcur =================
// 1024 threads; 8 lanes/row (16 consecutive floats each) -> coalesced.  (R5-verified body.)

__global__ __launch_bounds__(1024) void k_pmat(const float* __restrict__ w_gcn0,
                                               const float* __restrict__ w_gcn1,
                                               const float* __restrict__ w_rate0,
                                               const float* __restrict__ w_rate1,
                                               const float* __restrict__ w_alpha,
                                               float* __restrict__ Pt0, float* __restrict__ Pt1,
                                               float* __restrict__ Pt2, int* __restrict__ gcur) {
    __shared__ float V0[128], V1[128], V2[128];
    __shared__ float Q0[128], Q1[128], Q2[128];
    int t = threadIdx.x;
    if (t < KB) gcur[t] = 0;
    int r = t >> 3, seg = t & 7;
    {   // V0 = rowsum(w_rate0)
        const float* p = w_rate0 + r * 128 + seg * 16;
        float s = 0.f;
        #pragma unroll
        for (int k = 0; k < 16; ++k) s += p[k];
        s += __shfl_down(s, 4, 8); s += __shfl_down(s, 2, 8); s += __shfl_down(s, 1, 8);
        if (seg == 0) V0[r] = s;
    }
    if (t < 128) { V1[t] = w_rate1[t]; V2[t] = w_alpha[t]; }
    __syncthreads();
    {   // Q = w_gcn1 @ V
        const float* p = w_gcn1 + r * 128 + seg * 16;
        float q0 = 0.f, q1 = 0.f, q2 = 0.f;
        #pragma unroll
        for (int k = 0; k < 16; ++k) {
            float w = p[k]; int j = seg * 16 + k;
            q0 += w * V0[j]; q1 += w * V1[j]; q2 += w * V2[j];
        }
        q0 += __shfl_down(q0, 4, 8); q0 += __shfl_down(q0, 2, 8); q0 += __shfl_down(q0, 1, 8);
        q1 += __shfl_down(q1, 4, 8); q1 += __shfl_down(q1, 2, 8); q1 += __shfl_down(q1, 1, 8);
        q2 += __shfl_down(q2, 4, 8); q2 += __shfl_down(q2, 2, 8); q2 += __shfl_down(q2, 1, 8);
        if (seg == 0) { Q0[r] = q0; Q1[r] = q1; Q2[r] = q2; }
    }
    __syncthreads();
    {   // P = w_gcn0 @ Q
        const float* p = w_gcn0 + r * 128 + seg * 16;
        float q0 = 0.f, q1 = 0.f, q2 = 0.f;
        #pragma unroll
        for (int k = 0; k < 16; ++k) {
            float w = p[k]; int j = seg * 16 + k;
            q0 += w * Q0[j]; q1 += w * Q1[j]; q2 += w * Q2[j];
        }
        q0 += __shfl_down(q0, 4, 8); q0 += __shfl_down(q0, 2, 8); q0 += __shfl_down(q0, 1, 8);
        q1 += __shfl_down(q1, 4, 8); q1 += __shfl_down(q1, 2, 8); q1 += __shfl_down(q1, 1, 8);
        q2 += __shfl_down(q2, 4, 8); q2 += __shfl_down(q2, 2, 8); q2 += __shfl_down(q2, 1, 8);
        if (seg == 0) { Pt0[r] = q0; Pt1[r] = q1; Pt2[r] = q2; }
    }
}

// ================= D1: part (even blocks) ∥ proj (odd blocks), 782 x 512 =================
// part: 4096 edges/block, int4 loads, SINGLE-pass histogram with rank capture.
// proj: u4.xyz = h @ P, unroll-2 (two h float4 loads in flight). (.w filled by k_cnt.)

__global__ __launch_bounds__(512) void k_part_proj(const int* __restrict__ src, const int* __restrict__ dst,
                                                   int* __restrict__ gcur, unsigned int* __restrict__ pk,
                                                   const float* __restrict__ h,
                                                   const float* __restrict__ Pt0, const float* __restrict__ Pt1,
                                                   const float* __restrict__ Pt2,
                                                   float4* __restrict__ u4) {
    __shared__ int cnt[KB];
    __shared__ int base[KB];
    __shared__ alignas(16) float sP0[128], sP1[128], sP2[128];
    int t = threadIdx.x;
    int role = blockIdx.x & 1;
    int id = blockIdx.x >> 1;

    if (role == 0) {
        // ---------------- partition: pk = dst | srel<<17 ----------------
        if (t < KB) cnt[t] = 0;
        __syncthreads();
        int e0 = id * 4096 + t * 8;
        unsigned int pkv[8];
        int bkt[8], rnk[8];
        if (e0 + 8 <= EE) {
            int4 sa = *(const int4*)(src + e0);
            int4 sb = *(const int4*)(src + e0 + 4);
            int4 da = *(const int4*)(dst + e0);
            int4 db = *(const int4*)(dst + e0 + 4);
            int ss[8] = { sa.x, sa.y, sa.z, sa.w, sb.x, sb.y, sb.z, sb.w };
            int dd[8] = { da.x, da.y, da.z, da.w, db.x, db.y, db.z, db.w };
            #pragma unroll
            for (int i = 0; i < 8; ++i) {
                int b = ss[i] / RR;
                bkt[i] = b;
                pkv[i] = (unsigned int)dd[i] | ((unsigned int)(ss[i] - b * RR) << 17);
                rnk[i] = atomicAdd(&cnt[b], 1);        // rank within block, single pass
            }
        } else {
            #pragma unroll
            for (int i = 0; i < 8; ++i) {
                int e = e0 + i;
                if (e < EE) {
                    int s = src[e], d = dst[e];
                    int b = s / RR;
                    bkt[i] = b;
                    pkv[i] = (unsigned int)d | ((unsigned int)(s - b * RR) << 17);
                    rnk[i] = atomicAdd(&cnt[b], 1);
                } else bkt[i] = -1;
            }
        }
        __syncthreads();
        if (t < KB) base[t] = cnt[t] ? atomicAdd(&gcur[t], cnt[t]) : 0;   // gcur zeroed by k_pmat
        __syncthreads();
        #pragma unroll
        for (int i = 0; i < 8; ++i) {
            if (bkt[i] >= 0) {
                int rel = base[bkt[i]] + rnk[i];
                if (rel < CAP) pk[bkt[i] * CAP + rel] = pkv[i];   // overflow guard (stat. impossible)
            }
        }
    } else {
        // ---------------- raw projection u = h @ P, unroll-2 ----------------
        if (t < 128) { sP0[t] = Pt0[t]; sP1[t] = Pt1[t]; sP2[t] = Pt2[t]; }
        __syncthreads();
        int hw = t >> 5;       // 0..15
        int l32 = t & 31;
        int c4 = l32 * 4;
        float4 c0 = *(const float4*)(sP0 + c4);
        float4 c1 = *(const float4*)(sP1 + c4);
        float4 c2 = *(const float4*)(sP2 + c4);
        int nlo = id * 256;
        for (int i0 = 0; i0 < 256; i0 += 32) {
            int nodeA = nlo + i0 + hw;
            int nodeB = nodeA + 16;
            bool vA = nodeA < NN, vB = nodeB < NN;
            float4 ha = vA ? *(const float4*)(h + (size_t)nodeA * 128 + c4) : make_float4(0.f,0.f,0.f,0.f);
            float4 hb = vB ? *(const float4*)(h + (size_t)nodeB * 128 + c4) : make_float4(0.f,0.f,0.f,0.f);
            float a0 = ha.x * c0.x + ha.y * c0.y + ha.z * c0.z + ha.w * c0.w;
            float a1 = ha.x * c1.x + ha.y * c1.y + ha.z * c1.z + ha.w * c1.w;
            float a2 = ha.x * c2.x + ha.y * c2.y + ha.z * c2.z + ha.w * c2.w;
            float b0 = hb.x * c0.x + hb.y * c0.y + hb.z * c0.z + hb.w * c0.w;
            float b1 = hb.x * c1.x + hb.y * c1.y + hb.z * c1.z + hb.w * c1.w;
            float b2 = hb.x * c2.x + hb.y * c2.y + hb.z * c2.z + hb.w * c2.w;
            #pragma unroll
            for (int off = 16; off > 0; off >>= 1) {
                a0 += __shfl_down(a0, off, 32);
                a1 += __shfl_down(a1, off, 32);
                a2 += __shfl_down(a2, off, 32);
                b0 += __shfl_down(b0, off, 32);
                b1 += __shfl_down(b1, off, 32);
                b2 += __shfl_down(b2, off, 32);
            }
            if (l32 == 0) {
                if (vA) {
                    float* up = (float*)&u4[nodeA];
                    *(float2*)up = make_float2(a0, a1);   // .xy
                    up[2] = a2;                           // .z   (.w by k_cnt)
                }
                if (vB) {
                    float* up = (float*)&u4[nodeB];
                    *(float2*)up = make_float2(b0, b1);
                    up[2] = b2;
                }
            }
        }
    }
}

// ================= D2: cnt: degrees from pk -> nrm[]; stow nrm into u4.w =================

__global__ __launch_bounds__(1024) void k_cnt(const unsigned int* __restrict__ pk,
                                              const int* __restrict__ gcur,
                                              float* __restrict__ nrm, float4* __restrict__ u4) {
    __shared__ int c[RR];
    int b = blockIdx.x;
    int t = threadIdx.x;
    int nlo = b * RR;
    int nn = NN - nlo; if (nn > RR) nn = RR;
    if (nn <= 0) return;
    if (t < RR) c[t] = 0;
    __syncthreads();
    const unsigned int* P = pk + b * CAP;
    int m = gcur[b]; if (m > CAP) m = CAP;
    for (int i = t; i < m; i += 1024) atomicAdd(&c[P[i] >> 17], 1);
    __syncthreads();
    if (t < nn) {
        float nv = rsqrtf((float)c[t]);
        nrm[nlo + t] = nv;
        ((float*)&u4[nlo + t])[3] = nv;    // .w only
    }
}

// ================= D3/D4: bucketed aggregation; 4-deep pipelined gathers =================
// MODE 1: value = T[d].xyz * T[d].w (u4, .w = nrm[d]); store z = nrm^2 * acc
// MODE 2: value = T[d].xyz (z4 pre-scaled);            store p = nrm * acc

template<int MODE>
__global__ __launch_bounds__(1024) void k_agg(const unsigned int* __restrict__ pk,
                                              const int* __restrict__ gcur,
                                              const float4* __restrict__ T, const float* __restrict__ nrm,
                                              float4* __restrict__ outv) {
    __shared__ float s0[RR], s1[RR], s2[RR];
    int b = blockIdx.x;
    int t = threadIdx.x;
    int nlo = b * RR;
    int nn = NN - nlo; if (nn > RR) nn = RR;
    if (nn <= 0) return;
    if (t < RR) { s0[t] = 0.f; s1[t] = 0.f; s2[t] = 0.f; }
    __syncthreads();
    const unsigned int* P = pk + b * CAP;
    int m = gcur[b]; if (m > CAP) m = CAP;
    int i = t;
    for (; i + 3072 < m; i += 4096) {
        unsigned int w0 = P[i];
        unsigned int w1 = P[i + 1024];
        unsigned int w2 = P[i + 2048];
        unsigned int w3 = P[i + 3072];
        float4 v0 = T[w0 & 0x1FFFFu];
        float4 v1 = T[w1 & 0x1FFFFu];
        float4 v2 = T[w2 & 0x1FFFFu];
        float4 v3 = T[w3 & 0x1FFFFu];
        if (MODE == 1) {
            v0.x *= v0.w; v0.y *= v0.w; v0.z *= v0.w;
            v1.x *= v1.w; v1.y *= v1.w; v1.z *= v1.w;
            v2.x *= v2.w; v2.y *= v2.w; v2.z *= v2.w;
            v3.x *= v3.w; v3.y *= v3.w; v3.z *= v3.w;
        }
        int r0 = (int)(w0 >> 17), r1 = (int)(w1 >> 17), r2 = (int)(w2 >> 17), r3 = (int)(w3 >> 17);
        atomicAdd(&s0[r0], v0.x); atomicAdd(&s1[r0], v0.y); atomicAdd(&s2[r0], v0.z);
        atomicAdd(&s0[r1], v1.x); atomicAdd(&s1[r1], v1.y); atomicAdd(&s2[r1], v1.z);
        atomicAdd(&s0[r2], v2.x); atomicAdd(&s1[r2], v2.y); atomicAdd(&s2[r2], v2.z);
        atomicAdd(&s0[r3], v3.x); atomicAdd(&s1[r3], v3.y); atomicAdd(&s2[r3], v3.z);
    }
    for (; i < m; i += 1024) {
        unsigned int wa = P[i];
        float4 va = T[wa & 0x1FFFFu];
        float ax = va.x, ay = va.y, az = va.z;
        if (MODE == 1) { ax *= va.w; ay *= va.w; az *= va.w; }
        int ra = (int)(wa >> 17);
        atomicAdd(&s0[ra], ax); atomicAdd(&s1[ra], ay); atomicAdd(&s2[ra], az);
    }
    __syncthreads();
    for (int j = t; j < nn; j += 1024) {
        float nv = nrm[nlo + j];
        float sc = (MODE == 1) ? nv * nv : nv;
        outv[nlo + j] = make_float4(sc * s0[j], sc * s1[j], sc * s2[j], 0.f);
    }
}

// ================= D5: edge outputs: 4 edges/thread, int4 index loads, float4 stores =================

__global__ __launch_bounds__(256) void k_edge(const int* __restrict__ esrc, const int* __restrict__ edst,
                                              const int* __restrict__ sfake, const int* __restrict__ dfake,
                                              const float4* __restrict__ p4, float* __restrict__ out) {
    int t = threadIdx.x;
    int e0 = blockIdx.x * 1024 + t * 4;
    if (e0 >= EE) return;
    int4 s4  = *(const int4*)(esrc + e0);
    int4 d4  = *(const int4*)(edst + e0);
    int4 sf4 = *(const int4*)(sfake + e0);
    int4 df4 = *(const int4*)(dfake + e0);
    int ss[4] = { s4.x, s4.y, s4.z, s4.w };
    int dd[4] = { d4.x, d4.y, d4.z, d4.w };
    int sf[4] = { sf4.x, sf4.y, sf4.z, sf4.w };
    int df[4] = { df4.x, df4.y, df4.z, df4.w };
    float o0[4], o1[4], o2[4], o3[4], o4[4], o5[4];
    #pragma unroll
    for (int j = 0; j < 4; ++j) {
        int sfj = sf[j]; sfj = sfj < 0 ? 0 : (sfj >= NN ? NN - 1 : sfj);
        int dfj = df[j]; dfj = dfj < 0 ? 0 : (dfj >= NN ? NN - 1 : dfj);
        float4 ps = p4[ss[j]], pd = p4[dd[j]], psf = p4[sfj], pdf = p4[dfj];
        o0[j] = expf(ps.x + pd.x);
        o1[j] = expf(ps.y + pd.y);
        o2[j] = 1.f / (1.f + expf(-(ps.z * pd.z)));
        o3[j] = expf(psf.x + 128.f * pdf.y);
        o4[j] = expf(psf.y + pdf.y);
        o5[j] = 1.f / (1.f + expf(-(ps.z * pdf.z)));
    }
    *(float4*)(out + e0)                  = make_float4(o0[0], o0[1], o0[2], o0[3]);
    *(float4*)(out + (size_t)EE + e0)     = make_float4(o1[0], o1[1], o1[2], o1[3]);
    *(float4*)(out + (size_t)2 * EE + e0) = make_float4(o2[0], o2[1], o2[2], o2[3]);
    *(float4*)(out + (size_t)3 * EE + e0) = make_float4(o3[0], o3[1], o3[2], o3[3]);
    *(float4*)(out + (size_t)4 * EE + e0) = make_float4(o4[0], o4[1], o4[2], o4[3]);
    *(float4*)(out + (size_t)5 * EE + e0) = make_float4(o5[0], o5[1], o5[2], o5[3]);
}

// ---------------- launch ----------------

extern "C" void kernel_launch(void* const* d_in, const int* in_sizes, int n_in,
                              void* d_out, int out_size, void* d_ws, size_t ws_size,
                              hipStream_t stream) {
    const float* h       = (const float*)d_in[0];
    const float* w_gcn0  = (const float*)d_in[1];
    const float* w_gcn1  = (const float*)d_in[2];
    const float* w_rate0 = (const float*)d_in[3];
    const float* w_rate1 = (const float*)d_in[4];
    const float* w_alpha = (const float*)d_in[5];
    const int* edge_src  = (const int*)d_in[6];
    const int* edge_dst  = (const int*)d_in[7];
    const int* src_fake  = (const int*)d_in[8];
    const int* dst_fake  = (const int*)d_in[9];
    float* out = (float*)d_out;

    char* p = (char*)d_ws;
    auto alloc = [&](size_t bytes) {
        char* r = p;
        p += (bytes + 255) & ~(size_t)255;
        return r;
    };
    unsigned int* pk = (unsigned int*)alloc((size_t)KB * CAP * 4);   // 8.4 MB
    int* gcur   = (int*)alloc(KB * 4);
    float* nrm  = (float*)alloc((size_t)NN * 4);
    float4* u4  = (float4*)alloc((size_t)NN * 16);
    float4* z4  = (float4*)alloc((size_t)NN * 16);
    float4* p4  = (float4*)alloc((size_t)NN * 16);
    float* Pt0  = (float*)alloc(512);
    float* Pt1  = (float*)alloc(512);
    float* Pt2  = (float*)alloc(512);

    k_pmat<<<1, 1024, 0, stream>>>(w_gcn0, w_gcn1, w_rate0, w_rate1, w_alpha,
                                   Pt0, Pt1, Pt2, gcur);
    k_part_proj<<<2 * NPART, 512, 0, stream>>>(edge_src, edge_dst, gcur, pk, h,
                                               Pt0, Pt1, Pt2, u4);
    k_cnt<<<KB, 1024, 0, stream>>>(pk, gcur, nrm, u4);
    k_agg<1><<<KB, 1024, 0, stream>>>(pk, gcur, u4, nrm, z4);
    k_agg<2><<<KB, 1024, 0, stream>>>(pk, gcur, z4, nrm, p4);
    k_edge<<<(EE + 1023) / 1024, 256, 0, stream>>>(edge_src, edge_dst, src_fake, dst_fake, p4, out);
}